// Round 6
// baseline (1011.766 us; speedup 1.0000x reference)
//
#include <hip/hip_runtime.h>
#include <math.h>

#define N_ROWS 131072   // 32*64*64
#define D 64
#define K 512
#define BLK 256
#define ROWS_PER_BLK 128            // 2 threads per row
#define GRID (N_ROWS / ROWS_PER_BLK)  // 1024

// d_out layout (floats):
//   [0]                     loss
//   [1 .. 8388608]          quantized_st, NCHW [32,64,64,64]
//   [8388609]               perplexity
//   [8388610 .. +67108863]  encodings [131072, 512]
//
// d_ws layout (bytes):
//   [0, 2048)      unsigned int counts[512]
//   [2048, 2056)   unsigned long long loss_acc (fixed-point 2^-30, deterministic)
//   [4096, 6144)   float e2[512]

__global__ __launch_bounds__(256) void vq_e2_kernel(
    const float* __restrict__ emb, float* __restrict__ e2)
{
    int k = blockIdx.x * blockDim.x + threadIdx.x;
    if (k < K) {
        const float* e = emb + k * D;
        float s = 0.f;
        #pragma unroll
        for (int d = 0; d < D; ++d) s = fmaf(e[d], e[d], s);
        e2[k] = s;
    }
}

// Rounds 1-5 lesson: one thread per row needs ~150 live VGPRs; the scheduler
// always targets ~64 and pushes the x row to scratch -> 17 GB of L2 spill
// traffic = constant ~520 us. Structure fix: 2 threads/row, 32 dims each
// (8 named float4 = 32 VGPR), pair-combine with one __shfl_xor. Live set
// ~55 VGPR fits any occupancy target by construction.
#define FOR8(M) M(0) M(1) M(2) M(3) M(4) M(5) M(6) M(7)

__global__ __launch_bounds__(256)
__attribute__((amdgpu_waves_per_eu(1, 4)))
void vq_main_kernel(
    const float* __restrict__ in,     // [32,64,64,64] NCHW
    const float* __restrict__ emb,    // [512,64]
    const float* __restrict__ e2,     // [512]
    unsigned int* __restrict__ counts,
    unsigned long long* __restrict__ loss_acc,
    float* __restrict__ quant_out,    // NCHW
    float* __restrict__ enc_out)      // [N_ROWS, 512]
{
    __shared__ int s_idx[ROWS_PER_BLK];
    __shared__ double s_red[BLK];
    __shared__ unsigned int s_hist[K];

    const int tid  = threadIdx.x;
    const int half = tid & 1;               // which 32-dim half of the row
    const int r    = tid >> 1;              // row within block, 0..127
    const int n    = blockIdx.x * ROWS_PER_BLK + r;
    const int b    = n >> 12;               // n / 4096
    const int hw   = n & 4095;              // h*64 + w
    const float* xin = in + (size_t)b * 262144 + (size_t)(half * 32) * 4096 + hw;

    for (int k = tid; k < K; k += BLK) s_hist[k] = 0;
    __syncthreads();

    // this thread's 32 dims in 8 named float4 registers
#define LOADX(i) float4 x##i = make_float4(xin[(4*i+0)*4096], xin[(4*i+1)*4096], \
                                           xin[(4*i+2)*4096], xin[(4*i+3)*4096]);
    FOR8(LOADX)
#undef LOADX

    // argmin over codes: score = ||e||^2 - 2 x.e  (||x||^2 const per row, dropped)
    float s1 = INFINITY, s2 = INFINITY;
    int i1 = 0, i2 = 0;
    const float4* __restrict__ e4base =
        reinterpret_cast<const float4*>(emb) + half * 8;
    for (int k = 0; k < K; ++k) {
        const float4* __restrict__ e4 = e4base + k * 16;
        float a0 = 0.f, a1 = 0.f, a2 = 0.f, a3 = 0.f;
#define FMA4(i) { float4 ev = e4[i]; \
                  a0 = fmaf(x##i.x, ev.x, a0); \
                  a1 = fmaf(x##i.y, ev.y, a1); \
                  a2 = fmaf(x##i.z, ev.z, a2); \
                  a3 = fmaf(x##i.w, ev.w, a3); }
        FOR8(FMA4)
#undef FMA4
        float p = (a0 + a1) + (a2 + a3);
        p += __shfl_xor(p, 1, 64);          // pair-combine (both lanes get sum)
        float s = fmaf(-2.f, p, e2[k]);
        // identical in both pair lanes -> uniform within the pair
        if (s < s1) { s2 = s1; i2 = i1; s1 = s; i1 = k; }
        else if (s < s2) { s2 = s; i2 = k; }
    }

    // fp64 refinement when top-2 nearly tie (makes argmin fp64-exact).
    // Condition is pair-uniform, so the intra-pair shuffles are safe.
    if (s2 - s1 < 4e-3f) {
        const float* eA = emb + i1 * D + half * 32;
        const float* eB = emb + i2 * D + half * 32;
        double dA = 0.0, dB = 0.0;
        double t;
#define REF1(xc, off) \
        t = (double)(xc) - (double)eA[off]; dA = fma(t, t, dA); \
        t = (double)(xc) - (double)eB[off]; dB = fma(t, t, dB);
#define REF(i) REF1(x##i.x, 4*i+0) REF1(x##i.y, 4*i+1) \
               REF1(x##i.z, 4*i+2) REF1(x##i.w, 4*i+3)
        FOR8(REF)
#undef REF
#undef REF1
        dA += __shfl_xor(dA, 1, 64);
        dB += __shfl_xor(dB, 1, 64);
        if (dB < dA || (dB == dA && i2 < i1)) i1 = i2;
    }

    if (!half) {
        s_idx[r] = i1;
        atomicAdd(&s_hist[i1], 1u);
    }

    // quantized write (this thread's 32 dims, coalesced across lanes) + loss
    const float4* __restrict__ eq4 =
        reinterpret_cast<const float4*>(emb + (size_t)i1 * D) + half * 8;
    float* qout = quant_out + (size_t)b * 262144 + (size_t)(half * 32) * 4096 + hw;
    float lsum = 0.f;
#define WQ1(qc, xc, off) { float df = (qc) - (xc); lsum = fmaf(df, df, lsum); \
                           qout[(off) * 4096] = (qc); }
#define WQ(i) { float4 q = eq4[i]; \
                WQ1(q.x, x##i.x, 4*i+0) WQ1(q.y, x##i.y, 4*i+1) \
                WQ1(q.z, x##i.z, 4*i+2) WQ1(q.w, x##i.w, 4*i+3) }
    FOR8(WQ)
#undef WQ
#undef WQ1

    // block loss reduction (double), then one deterministic fixed-point atomic
    s_red[tid] = (double)lsum;
    __syncthreads();
    for (int s = BLK / 2; s > 0; s >>= 1) {
        if (tid < s) s_red[tid] += s_red[tid + s];
        __syncthreads();
    }
    if (tid == 0) {
        unsigned long long q =
            (unsigned long long)(long long)llrint(s_red[0] * 1073741824.0);
        atomicAdd(loss_acc, q);
    }

    // flush histogram (integer atomics: deterministic)
    for (int k = tid; k < K; k += BLK) {
        unsigned int c = s_hist[k];
        if (c) atomicAdd(&counts[k], c);
    }

    // cooperative coalesced one-hot writes: 128 rows x 512 floats
    float* enc = enc_out + (size_t)blockIdx.x * (size_t)(ROWS_PER_BLK * K);
    const int h2 = tid >> 7;            // 0 or 1
    const int col4 = (tid & 127) * 4;   // column start within row
    for (int rr = 0; rr < ROWS_PER_BLK; rr += 2) {
        int row = rr + h2;
        int ir = s_idx[row];
        float4 v;
        v.x = (col4 + 0 == ir) ? 1.f : 0.f;
        v.y = (col4 + 1 == ir) ? 1.f : 0.f;
        v.z = (col4 + 2 == ir) ? 1.f : 0.f;
        v.w = (col4 + 3 == ir) ? 1.f : 0.f;
        *reinterpret_cast<float4*>(enc + (size_t)row * K + col4) = v;
    }
}

__global__ __launch_bounds__(512) void vq_final_kernel(
    const unsigned int* __restrict__ counts,
    const unsigned long long* __restrict__ loss_acc,
    float* __restrict__ out_loss,
    float* __restrict__ out_perp)
{
    __shared__ double sp[512];
    int t = threadIdx.x;
    double p = (double)counts[t] / (double)N_ROWS;
    sp[t] = p * log(p + 1e-10);
    __syncthreads();
    for (int s = 256; s > 0; s >>= 1) {
        if (t < s) sp[t] += sp[t + s];
        __syncthreads();
    }
    if (t == 0) {
        double ls = (double)(long long)(*loss_acc) * (1.0 / 1073741824.0);
        *out_loss = (float)(0.25 * ls / 8388608.0);
        *out_perp = (float)exp(-sp[0]);
    }
}

extern "C" void kernel_launch(void* const* d_in, const int* in_sizes, int n_in,
                              void* d_out, int out_size, void* d_ws, size_t ws_size,
                              hipStream_t stream) {
    const float* in  = (const float*)d_in[0];
    const float* emb = (const float*)d_in[1];
    float* out = (float*)d_out;

    unsigned int* counts = (unsigned int*)d_ws;
    unsigned long long* loss_acc = (unsigned long long*)((char*)d_ws + 2048);
    float* e2 = (float*)((char*)d_ws + 4096);

    hipMemsetAsync(d_ws, 0, 2056, stream);
    vq_e2_kernel<<<2, 256, 0, stream>>>(emb, e2);
    vq_main_kernel<<<GRID, BLK, 0, stream>>>(in, emb, e2, counts, loss_acc,
                                             out + 1, out + 8388610);
    vq_final_kernel<<<1, 512, 0, stream>>>(counts, loss_acc, out, out + 8388609);
}

// Round 7
// 352.592 us; speedup vs baseline: 2.8695x; 2.8695x over previous
//
#include <hip/hip_runtime.h>
#include <math.h>

#define N_ROWS 131072   // 32*64*64
#define D 64
#define K 512
#define BLK 512
#define GRID (N_ROWS / BLK)   // 256 blocks -> exactly 1 per CU

// d_out layout (floats):
//   [0]                     loss
//   [1 .. 8388608]          quantized_st, NCHW [32,64,64,64]
//   [8388609]               perplexity
//   [8388610 .. +67108863]  encodings [131072, 512]
//
// d_ws layout (bytes):
//   [0, 2048)      unsigned int counts[512]
//   [2048, 2056)   unsigned long long loss_acc (fixed-point 2^-30, deterministic)
//   [4096, 6144)   float e2[512]

__global__ __launch_bounds__(256) void vq_e2_kernel(
    const float* __restrict__ emb, float* __restrict__ e2)
{
    int k = blockIdx.x * blockDim.x + threadIdx.x;
    if (k < K) {
        const float* e = emb + k * D;
        float s = 0.f;
        #pragma unroll
        for (int d = 0; d < D; ++d) s = fmaf(e[d], e[d], s);
        e2[k] = s;
    }
}

// Rounds 1-6 lesson: the k-loop was latency-bound on the per-iteration
// e-row loads (scalar-cache-missing s_loads rounds 1-5, VMEM round 6) --
// VALUBusy pinned at ~18% regardless of register shaping. Fix: codebook
// lives in LDS (128 KB, broadcast ds_read_b128 per k, conflict-free);
// x row lives in 16 named float4s PINNED via opaque asm so the scheduler
// cannot sink the global loads back into the loop.
#define FOR16(M) M(0) M(1) M(2) M(3) M(4) M(5) M(6) M(7) \
                 M(8) M(9) M(10) M(11) M(12) M(13) M(14) M(15)

__global__ __launch_bounds__(BLK, 2) void vq_main_kernel(
    const float* __restrict__ in,     // [32,64,64,64] NCHW
    const float* __restrict__ emb,    // [512,64]
    const float* __restrict__ e2,     // [512]
    unsigned int* __restrict__ counts,
    unsigned long long* __restrict__ loss_acc,
    float* __restrict__ quant_out,    // NCHW
    float* __restrict__ enc_out)      // [N_ROWS, 512]
{
    __shared__ float s_emb[K * D];          // 128 KB codebook
    __shared__ int s_idx[BLK];              // 2 KB
    __shared__ unsigned int s_hist[K];      // 2 KB
    __shared__ double s_red[BLK];           // 4 KB

    const int tid = threadIdx.x;
    const int n = blockIdx.x * BLK + tid;   // row index in [B,H,W] order
    const int b = n >> 12;                  // n / 4096
    const int hw = n & 4095;                // h*64 + w
    const float* xin = in + (size_t)b * 262144 + hw;

    // stage codebook -> LDS (coalesced float4), zero histogram
    {
        const float4* g4 = reinterpret_cast<const float4*>(emb);
        float4* l4 = reinterpret_cast<float4*>(s_emb);
        #pragma unroll
        for (int i = 0; i < (K * D / 4) / BLK; ++i)   // 16 iters
            l4[tid + i * BLK] = g4[tid + i * BLK];
    }
    for (int k = tid; k < K; k += BLK) s_hist[k] = 0;

    // load x row into named registers (coalesced across lanes per d),
    // then pin them: opaque asm redefines the values so they cannot be
    // rematerialized/sunk into the k-loop as global loads.
#define LOADX(i) float4 x##i = make_float4(xin[(4*i+0)*4096], xin[(4*i+1)*4096], \
                                           xin[(4*i+2)*4096], xin[(4*i+3)*4096]);
    FOR16(LOADX)
#undef LOADX
#define PINX(i) asm volatile("" : "+v"(x##i.x), "+v"(x##i.y), \
                                  "+v"(x##i.z), "+v"(x##i.w));
    FOR16(PINX)
#undef PINX

    __syncthreads();

    // argmin over codes: score = ||e||^2 - 2 x.e  (||x||^2 const per row, dropped)
    // e row comes from LDS at a wave-uniform address -> pure broadcast.
    float s1 = INFINITY, s2 = INFINITY;
    int i1 = 0, i2 = 0;
    for (int k = 0; k < K; ++k) {
        const float4* __restrict__ e4 =
            reinterpret_cast<const float4*>(s_emb + k * D);
        float a0 = 0.f, a1 = 0.f, a2 = 0.f, a3 = 0.f;
#define FMA4(i) { float4 ev = e4[i]; \
                  a0 = fmaf(x##i.x, ev.x, a0); \
                  a1 = fmaf(x##i.y, ev.y, a1); \
                  a2 = fmaf(x##i.z, ev.z, a2); \
                  a3 = fmaf(x##i.w, ev.w, a3); }
        FOR16(FMA4)
#undef FMA4
        float s = e2[k] - 2.f * ((a0 + a1) + (a2 + a3));
        if (s < s1) { s2 = s1; i2 = i1; s1 = s; i1 = k; }
        else if (s < s2) { s2 = s; i2 = k; }
    }

    // fp64 refinement when top-2 nearly tie (makes argmin fp64-exact)
    if (s2 - s1 < 4e-3f) {
        const float* eA = s_emb + i1 * D;
        const float* eB = s_emb + i2 * D;
        double dA = 0.0, dB = 0.0;
        double t;
#define REF1(xc, off) \
        t = (double)(xc) - (double)eA[off]; dA = fma(t, t, dA); \
        t = (double)(xc) - (double)eB[off]; dB = fma(t, t, dB);
#define REF(i) REF1(x##i.x, 4*i+0) REF1(x##i.y, 4*i+1) \
               REF1(x##i.z, 4*i+2) REF1(x##i.w, 4*i+3)
        FOR16(REF)
#undef REF
#undef REF1
        if (dB < dA || (dB == dA && i2 < i1)) i1 = i2;
    }

    s_idx[tid] = i1;
    atomicAdd(&s_hist[i1], 1u);

    // quantized write (NCHW, coalesced across lanes per d) + loss partial
    const float4* __restrict__ eq4 =
        reinterpret_cast<const float4*>(s_emb + i1 * D);
    float* qout = quant_out + (size_t)b * 262144 + hw;
    float lsum = 0.f;
#define WQ1(qc, xc, off) { float df = (qc) - (xc); lsum = fmaf(df, df, lsum); \
                           qout[(off) * 4096] = (qc); }
#define WQ(i) { float4 q = eq4[i]; \
                WQ1(q.x, x##i.x, 4*i+0) WQ1(q.y, x##i.y, 4*i+1) \
                WQ1(q.z, x##i.z, 4*i+2) WQ1(q.w, x##i.w, 4*i+3) }
    FOR16(WQ)
#undef WQ
#undef WQ1

    // block loss reduction (double), one deterministic fixed-point atomic
    s_red[tid] = (double)lsum;
    __syncthreads();
    for (int s = BLK / 2; s > 0; s >>= 1) {
        if (tid < s) s_red[tid] += s_red[tid + s];
        __syncthreads();
    }
    if (tid == 0) {
        unsigned long long q =
            (unsigned long long)(long long)llrint(s_red[0] * 1073741824.0);
        atomicAdd(loss_acc, q);
    }

    // flush histogram (integer atomics: deterministic)
    for (int k = tid; k < K; k += BLK) {
        unsigned int c = s_hist[k];
        if (c) atomicAdd(&counts[k], c);
    }

    // cooperative coalesced one-hot writes: 512 rows x 512 floats.
    // threads split into 4 groups of 128; each group covers one row per step.
    float* enc = enc_out + (size_t)blockIdx.x * (size_t)(BLK * K);
    const int grp = tid >> 7;           // 0..3
    const int col4 = (tid & 127) * 4;   // column start within row
    for (int rr = 0; rr < BLK; rr += 4) {
        int row = rr + grp;
        int ir = s_idx[row];
        float4 v;
        v.x = (col4 + 0 == ir) ? 1.f : 0.f;
        v.y = (col4 + 1 == ir) ? 1.f : 0.f;
        v.z = (col4 + 2 == ir) ? 1.f : 0.f;
        v.w = (col4 + 3 == ir) ? 1.f : 0.f;
        *reinterpret_cast<float4*>(enc + (size_t)row * K + col4) = v;
    }
}

__global__ __launch_bounds__(512) void vq_final_kernel(
    const unsigned int* __restrict__ counts,
    const unsigned long long* __restrict__ loss_acc,
    float* __restrict__ out_loss,
    float* __restrict__ out_perp)
{
    __shared__ double sp[512];
    int t = threadIdx.x;
    double p = (double)counts[t] / (double)N_ROWS;
    sp[t] = p * log(p + 1e-10);
    __syncthreads();
    for (int s = 256; s > 0; s >>= 1) {
        if (t < s) sp[t] += sp[t + s];
        __syncthreads();
    }
    if (t == 0) {
        double ls = (double)(long long)(*loss_acc) * (1.0 / 1073741824.0);
        *out_loss = (float)(0.25 * ls / 8388608.0);
        *out_perp = (float)exp(-sp[0]);
    }
}

extern "C" void kernel_launch(void* const* d_in, const int* in_sizes, int n_in,
                              void* d_out, int out_size, void* d_ws, size_t ws_size,
                              hipStream_t stream) {
    const float* in  = (const float*)d_in[0];
    const float* emb = (const float*)d_in[1];
    float* out = (float*)d_out;

    unsigned int* counts = (unsigned int*)d_ws;
    unsigned long long* loss_acc = (unsigned long long*)((char*)d_ws + 2048);
    float* e2 = (float*)((char*)d_ws + 4096);

    hipMemsetAsync(d_ws, 0, 2056, stream);
    vq_e2_kernel<<<2, 256, 0, stream>>>(emb, e2);
    vq_main_kernel<<<GRID, BLK, 0, stream>>>(in, emb, e2, counts, loss_acc,
                                             out + 1, out + 8388610);
    vq_final_kernel<<<1, 512, 0, stream>>>(counts, loss_acc, out, out + 8388609);
}